// Round 19
// baseline (643.423 us; speedup 1.0000x reference)
//
#include <hip/hip_runtime.h>

// Flux2 double-stream attention block, bf16 MFMA pipeline, f32 final output.
// Stages: fused cvt(f32->bf16) -> QKV GEMM (8-phase 256^2, LDS-BW plateau
//         ~875 TF, 6 schedule variants identical) -> RMSnorm+RoPE(+V^T) ->
//         flash attn (3-buf) -> out GEMM (256x192 tiles, one-round grid 224).
// ws layout (bytes):
//   [0,           22020096)  A_in bf16 [3584][3072]   } later aliased by V^T [24][128][3584]
//   [22020096,   135266304)  Wq bf16: img [9216][3072] then enc } later aliased by attn_out
//   [135266304,  173015040)  Wo bf16: img [3072][3072] then enc
//   [173015040,  239075328)  qkv bf16 [3584][9216]
// peak ws = 239,075,328 B.

typedef unsigned short u16;
typedef __attribute__((ext_vector_type(2))) unsigned short u16x2;
typedef __attribute__((ext_vector_type(4))) unsigned short u16x4;
typedef __attribute__((ext_vector_type(8))) unsigned short u16x8;
typedef __attribute__((ext_vector_type(8))) short bf16x8;
typedef __attribute__((ext_vector_type(4))) float f32x4;
typedef __attribute__((ext_vector_type(16))) float f32x16;
typedef __attribute__((ext_vector_type(4))) unsigned u32x4;

#define DEV __device__ __forceinline__

DEV u16 f2bf(float f) {
  unsigned u = __builtin_bit_cast(unsigned, f);
  u = (u + 0x7FFFu + ((u >> 16) & 1u)) >> 16;   // RNE
  return (u16)u;
}
DEV float bf2f(u16 s) { return __builtin_bit_cast(float, (unsigned)s << 16); }

DEV void store_out(u16* p, float v)  { *p = f2bf(v); }
DEV void store_out(float* p, float v) { *p = v; }

#define AS1(p) (const __attribute__((address_space(1))) void*)(p)
#define AS3(p) (__attribute__((address_space(3))) void*)(p)
#define GLL16(g, l) __builtin_amdgcn_global_load_lds(AS1(g), AS3(l), 16, 0, 0)

#define BAR() do { asm volatile("" ::: "memory"); __builtin_amdgcn_s_barrier(); \
                   asm volatile("" ::: "memory"); } while (0)
#define LGKM0() asm volatile("s_waitcnt lgkmcnt(0)" ::: "memory")
#define VMC8() asm volatile("s_waitcnt vmcnt(8)" ::: "memory")
#define VMC6() asm volatile("s_waitcnt vmcnt(6)" ::: "memory")
#define VMC5() asm volatile("s_waitcnt vmcnt(5)" ::: "memory")
#define VMC0() asm volatile("s_waitcnt vmcnt(0)" ::: "memory")

// ---------------- fused fp32 -> bf16 convert (6 segments, 1 dispatch) -------
__global__ __launch_bounds__(256) void cvt_all(
    const float* __restrict__ s0, const float* __restrict__ s1,
    const float* __restrict__ s2, const float* __restrict__ s3,
    const float* __restrict__ s4, const float* __restrict__ s5,
    u16* __restrict__ ws16) {
  constexpr int B1 = 393216, B2 = 2752512, B3 = 9830400,
                B4 = 16908288, B5 = 19267584, B6 = 21626880;
  int i = blockIdx.x * blockDim.x + threadIdx.x;
  int stride = gridDim.x * blockDim.x;
  for (; i < B6; i += stride) {
    const float* src; size_t off; u16* dst;
    if (i < B1)      { src = s0; off = i;      dst = ws16; }
    else if (i < B2) { src = s1; off = i - B1; dst = ws16 + 1572864; }
    else if (i < B3) { src = s2; off = i - B2; dst = ws16 + 11010048; }
    else if (i < B4) { src = s3; off = i - B3; dst = ws16 + 39321600; }
    else if (i < B5) { src = s4; off = i - B4; dst = ws16 + 67633152; }
    else             { src = s5; off = i - B5; dst = ws16 + 77070336; }
    float4 v = reinterpret_cast<const float4*>(src)[off];
    u16x4 o;
    o.x = f2bf(v.x); o.y = f2bf(v.y); o.z = f2bf(v.z); o.w = f2bf(v.w);
    reinterpret_cast<u16x4*>(dst)[off] = o;
  }
}

// ---------------- GEMM: 8-phase 256x256, BK=64 (QKV; R18 form) --------------
template <typename OT>
__global__ __launch_bounds__(512, 2) void gemm256(
    const u16* __restrict__ A,
    const u16* __restrict__ Bimg, const u16* __restrict__ Benc,
    const float* __restrict__ biasImg, const float* __restrict__ biasEnc,
    OT* __restrict__ Cimg, OT* __restrict__ Cenc,
    int N, int K, int split) {
  const int bid = blockIdx.x;
  const int ntn = N >> 8;
  const int CN = ntn >> 2;
  const int x = bid & 7, i5 = bid >> 3;
  const int mt = (x >> 2) * 7 + i5 / CN;
  const int nt = (x & 3) * CN + i5 % CN;
  const int m0 = mt << 8, n0 = nt << 8;
  const u16* B = (m0 < split) ? Benc : Bimg;
  const float* bias = (m0 < split) ? biasEnc : biasImg;

  __shared__ u16 lds[2][2][2][8192];  // [dbuf][A=0/B=1][half][16KB] = 128 KiB

  const int tid = threadIdx.x, w = tid >> 6, lane = tid & 63;
  const int wm = w >> 2, wn = w & 3;
  const int q = lane & 15, hi = lane >> 4;
  const size_t ldb = (size_t)K * 2;

  f32x4 acc[8][4];
#pragma unroll
  for (int i = 0; i < 8; ++i)
#pragma unroll
    for (int j = 0; j < 4; ++j)
#pragma unroll
      for (int r = 0; r < 4; ++r) acc[i][j][r] = 0.f;

  auto STG_B = [&](int kt, int h) {
    const int d = kt & 1;
    char* dst = (char*)&lds[d][1][h][0] + w * 1024 + lane * 16;
#pragma unroll
    for (int g = 0; g < 2; ++g) {
      const int n = g * 8 + w;
      const char* src = (const char*)B + (size_t)(n0 + h * 128 + (n >> 1) * 16 + q) * ldb
                        + (size_t)kt * 128 + (n & 1) * 64 + hi * 16;
      GLL16(src, dst + g * 8192);
    }
  };
  auto STG_A = [&](int kt, int g) {
    const int d = kt & 1;
#pragma unroll
    for (int h = 0; h < 2; ++h) {
      const int n = g * 8 + w;
      const char* src = (const char*)A + (size_t)(m0 + h * 128 + (n >> 1) * 16 + q) * ldb
                        + (size_t)kt * 128 + (n & 1) * 64 + hi * 16;
      GLL16(src, (char*)&lds[d][0][h][0] + n * 1024 + lane * 16);
    }
  };
  auto LDA = [&](int d, int i, int ks) -> bf16x8 {
    return *(const bf16x8*)((const char*)&lds[d][0][wm][0] + (i * 2 + ks) * 1024 + lane * 16);
  };
  auto LDB = [&](int d, int j, int ks) -> bf16x8 {
    return *(const bf16x8*)((const char*)&lds[d][1][wn >> 1][0]
                            + (((wn & 1) * 4 + j) * 2 + ks) * 1024 + lane * 16);
  };

  bf16x8 bfr[4][2];
  auto PH = [&](int d, int ph, auto stageFn, int wmode) {
    if (ph == 0) {
#pragma unroll
      for (int j = 0; j < 4; ++j)
#pragma unroll
        for (int ks = 0; ks < 2; ++ks) bfr[j][ks] = LDB(d, j, ks);
    }
    bf16x8 af[2][2];
#pragma unroll
    for (int m = 0; m < 2; ++m)
#pragma unroll
      for (int ks = 0; ks < 2; ++ks) af[m][ks] = LDA(d, 2 * ph + m, ks);
    stageFn();
    BAR();
    LGKM0();
    __builtin_amdgcn_s_setprio(1);
#pragma unroll
    for (int m = 0; m < 2; ++m)
#pragma unroll
      for (int j = 0; j < 4; ++j)
#pragma unroll
        for (int ks = 0; ks < 2; ++ks)
          acc[2 * ph + m][j] = __builtin_amdgcn_mfma_f32_16x16x32_bf16(
              af[m][ks], bfr[j][ks], acc[2 * ph + m][j], 0, 0, 0);
    __builtin_amdgcn_s_setprio(0);
    if (wmode == 1)      VMC6();
    else if (wmode == 2) VMC0();
    BAR();
  };

  const int NT2 = K >> 7;
  STG_B(0, 0); STG_B(0, 1); STG_A(0, 0); STG_A(0, 1);
  STG_B(1, 0); STG_B(1, 1); STG_A(1, 0);
  VMC6();
  BAR();
  for (int t = 0; t < NT2; ++t) {
    const bool full = (t + 1 < NT2);
    const int w3 = full ? 1 : 2;
    PH(0, 0, [&] { STG_A(2 * t + 1, 1); }, 0);
    PH(0, 1, [&] { if (full) STG_B(2 * t + 2, 0); }, 0);
    PH(0, 2, [&] { if (full) STG_B(2 * t + 2, 1); }, 0);
    PH(0, 3, [&] { if (full) STG_A(2 * t + 2, 0); }, w3);
    PH(1, 0, [&] { if (full) STG_A(2 * t + 2, 1); }, 0);
    PH(1, 1, [&] { if (full) STG_B(2 * t + 3, 0); }, 0);
    PH(1, 2, [&] { if (full) STG_B(2 * t + 3, 1); }, 0);
    PH(1, 3, [&] { if (full) STG_A(2 * t + 3, 0); }, w3);
  }

#pragma unroll
  for (int i = 0; i < 8; ++i) {
    int rbase = m0 + wm * 128 + i * 16 + (hi << 2);
#pragma unroll
    for (int j = 0; j < 4; ++j) {
      int col = n0 + wn * 64 + j * 16 + q;
      float bv = bias ? bias[col] : 0.f;
#pragma unroll
      for (int r = 0; r < 4; ++r) {
        int row = rbase + r;
        float v = acc[i][j][r] + bv;
        if (row < split) store_out(&Cenc[(size_t)row * N + col], v);
        else             store_out(&Cimg[(size_t)(row - split) * N + col], v);
      }
    }
  }
}

// ---------------- out GEMM: 8-phase 256x192, BK=64, one-round grid ----------
// R19: N=3072 with 256-wide tiles gave 168 blocks on 256 CUs (66% util, one
// round). BN=192 -> grid 14x16 = 224 blocks (87.5%), per-block cost x0.75.
// B is a SINGLE 24 KB region (12 rowgrps x 2 ks units); all 6 B-frags are
// register-held from phase 0 -> B region dead after ph0 (same deadness rule
// as gemm256's B-halves). Stage schedule per iter:
//   ph0:A(2t+1,g1) ph1:B3(2t+2) ph3:A(2t+2,g0)+VMC5 ph4:A(2t+2,g1)
//   ph5:B3(2t+3) ph7:A(2t+3,g0)+VMC5        (tail iter: VMC0)
// Wait audit: at ph3's wait, 5 newer glls (B3=3 + A-g0=2) in flight -> the
// awaited kt(2t+1) A-g1 (issued ph0) has landed. At ph7: newer = B3+A-g0 = 5
// -> kt(2t+2)'s last stage (A-g1 @ ph4) landed. Prologue 12 glls, VMC5 ->
// kt0's 7 oldest landed.
__global__ __launch_bounds__(512, 2) void gemm192(
    const u16* __restrict__ A,
    const u16* __restrict__ Bimg, const u16* __restrict__ Benc,
    const float* __restrict__ biasImg, const float* __restrict__ biasEnc,
    float* __restrict__ Cimg, float* __restrict__ Cenc,
    int N, int K, int split) {
  const int bid = blockIdx.x;             // 224 = 8 XCD x 28
  const int x = bid & 7, i5 = bid >> 3;
  const int mt = (x >> 2) * 7 + i5 / 4;   // 14 mt
  const int nt = (x & 3) * 4 + i5 % 4;    // 16 nt
  const int m0 = mt << 8, n0 = nt * 192;
  const u16* B = (m0 < split) ? Benc : Bimg;
  const float* bias = (m0 < split) ? biasEnc : biasImg;

  __shared__ u16 lds_a[2][2][8192];   // [dbuf][half][16 units] = 64 KiB
  __shared__ u16 lds_b[2][12288];     // [dbuf][24 units]       = 48 KiB

  const int tid = threadIdx.x, w = tid >> 6, lane = tid & 63;
  const int wm = w >> 2, wn = w & 3;
  const int q = lane & 15, hi = lane >> 4;
  const size_t ldb = (size_t)K * 2;

  f32x4 acc[8][3];
#pragma unroll
  for (int i = 0; i < 8; ++i)
#pragma unroll
    for (int j = 0; j < 3; ++j)
#pragma unroll
      for (int r = 0; r < 4; ++r) acc[i][j][r] = 0.f;

  auto STG_B3 = [&](int kt) {           // 3 glls: whole 192x64 B tile
    const int d = kt & 1;
    char* dst = (char*)&lds_b[d][0] + w * 1024 + lane * 16;
#pragma unroll
    for (int g = 0; g < 3; ++g) {
      const int n = g * 8 + w;
      const char* src = (const char*)B + (size_t)(n0 + (n >> 1) * 16 + q) * ldb
                        + (size_t)kt * 128 + (n & 1) * 64 + hi * 16;
      GLL16(src, dst + g * 8192);
    }
  };
  auto STG_A = [&](int kt, int g) {     // 2 glls: unit-group g, both halves
    const int d = kt & 1;
#pragma unroll
    for (int h = 0; h < 2; ++h) {
      const int n = g * 8 + w;
      const char* src = (const char*)A + (size_t)(m0 + h * 128 + (n >> 1) * 16 + q) * ldb
                        + (size_t)kt * 128 + (n & 1) * 64 + hi * 16;
      GLL16(src, (char*)&lds_a[d][h][0] + n * 1024 + lane * 16);
    }
  };
  auto LDA = [&](int d, int i, int ks) -> bf16x8 {
    return *(const bf16x8*)((const char*)&lds_a[d][wm][0] + (i * 2 + ks) * 1024 + lane * 16);
  };
  auto LDB = [&](int d, int j, int ks) -> bf16x8 {
    return *(const bf16x8*)((const char*)&lds_b[d][0]
                            + ((wn * 3 + j) * 2 + ks) * 1024 + lane * 16);
  };

  bf16x8 bfr[3][2];
  auto PH = [&](int d, int ph, auto stageFn, int wmode) {
    if (ph == 0) {
#pragma unroll
      for (int j = 0; j < 3; ++j)
#pragma unroll
        for (int ks = 0; ks < 2; ++ks) bfr[j][ks] = LDB(d, j, ks);
    }
    bf16x8 af[2][2];
#pragma unroll
    for (int m = 0; m < 2; ++m)
#pragma unroll
      for (int ks = 0; ks < 2; ++ks) af[m][ks] = LDA(d, 2 * ph + m, ks);
    stageFn();
    BAR();
    LGKM0();
    __builtin_amdgcn_s_setprio(1);
#pragma unroll
    for (int m = 0; m < 2; ++m)
#pragma unroll
      for (int j = 0; j < 3; ++j)
#pragma unroll
        for (int ks = 0; ks < 2; ++ks)
          acc[2 * ph + m][j] = __builtin_amdgcn_mfma_f32_16x16x32_bf16(
              af[m][ks], bfr[j][ks], acc[2 * ph + m][j], 0, 0, 0);
    __builtin_amdgcn_s_setprio(0);
    if (wmode == 1)      VMC5();
    else if (wmode == 2) VMC0();
    BAR();
  };

  const int NT2 = K >> 7;
  STG_B3(0); STG_A(0, 0); STG_A(0, 1);
  STG_B3(1); STG_A(1, 0);
  VMC5();   // 12 glls out; newest 5 = kt1's -> kt0 fully landed
  BAR();
  for (int t = 0; t < NT2; ++t) {
    const bool full = (t + 1 < NT2);
    const int w3 = full ? 1 : 2;
    PH(0, 0, [&] { STG_A(2 * t + 1, 1); }, 0);
    PH(0, 1, [&] { if (full) STG_B3(2 * t + 2); }, 0);
    PH(0, 2, [&] {}, 0);
    PH(0, 3, [&] { if (full) STG_A(2 * t + 2, 0); }, w3);
    PH(1, 0, [&] { if (full) STG_A(2 * t + 2, 1); }, 0);
    PH(1, 1, [&] { if (full) STG_B3(2 * t + 3); }, 0);
    PH(1, 2, [&] {}, 0);
    PH(1, 3, [&] { if (full) STG_A(2 * t + 3, 0); }, w3);
  }

  // epilogue: row = m0 + wm*128 + i*16 + hi*4 + r, col = n0 + wn*48 + j*16 + q
#pragma unroll
  for (int i = 0; i < 8; ++i) {
    int rbase = m0 + wm * 128 + i * 16 + (hi << 2);
#pragma unroll
    for (int j = 0; j < 3; ++j) {
      int col = n0 + wn * 48 + j * 16 + q;
      float bv = bias ? bias[col] : 0.f;
#pragma unroll
      for (int r = 0; r < 4; ++r) {
        int row = rbase + r;
        float v = acc[i][j][r] + bv;
        if (row < split) Cenc[(size_t)row * N + col] = v;
        else             Cimg[(size_t)(row - split) * N + col] = v;
      }
    }
  }
}

// ---------------- per-head RMSnorm(q,k) + RoPE(q,k), emit V^T -----------------
// Q pre-scaled by log2(e)/sqrt(128) so attn scores land in log2 units.
__global__ __launch_bounds__(256) void norm_rope(
    u16* __restrict__ qkv, u16* __restrict__ vt,
    const float* __restrict__ cosT, const float* __restrict__ sinT,
    const float* __restrict__ nqw_img, const float* __restrict__ nkw_img,
    const float* __restrict__ nqw_enc, const float* __restrict__ nkw_enc) {
  const int h = blockIdx.y;
  const int s0 = blockIdx.x * 64;
  const int tid = threadIdx.x, w = tid >> 6, lane = tid & 63;
  const bool enc = (s0 < 512);
  const float* nqw = enc ? nqw_enc : nqw_img;
  const float* nkw = enc ? nkw_enc : nkw_img;
  const float SCL = 0.12751743f;  // log2(e)/sqrt(128)
  const float wq0 = nqw[2 * lane], wq1 = nqw[2 * lane + 1];
  const float wk0 = nkw[2 * lane], wk1 = nkw[2 * lane + 1];
  u16x8 va0, va1, vb0, vb1;
#pragma unroll
  for (int r = 0; r < 16; ++r) {
    const int s = s0 + w * 16 + r;
    const size_t rowb = (size_t)s * 9216 + h * 128 + 2 * lane;
    float2 cv = *(const float2*)&cosT[(size_t)s * 128 + 2 * lane];
    float2 sv = *(const float2*)&sinT[(size_t)s * 128 + 2 * lane];
    {  // Q
      u16x2 qu = *(u16x2*)&qkv[rowb];
      float x0 = bf2f(qu.x), x1 = bf2f(qu.y);
      float ss = x0 * x0 + x1 * x1;
#pragma unroll
      for (int d = 1; d < 64; d <<= 1) ss += __shfl_xor(ss, d);
      float rms = rsqrtf(ss * (1.0f / 128.0f) + 1e-5f);
      x0 *= rms * wq0; x1 *= rms * wq1;
      float o0 = (x0 * cv.x - x1 * sv.x) * SCL;
      float o1 = (x1 * cv.y + x0 * sv.y) * SCL;
      u16x2 ou; ou.x = f2bf(o0); ou.y = f2bf(o1);
      *(u16x2*)&qkv[rowb] = ou;
    }
    {  // K
      u16x2 ku = *(u16x2*)&qkv[rowb + 3072];
      float x0 = bf2f(ku.x), x1 = bf2f(ku.y);
      float ss = x0 * x0 + x1 * x1;
#pragma unroll
      for (int d = 1; d < 64; d <<= 1) ss += __shfl_xor(ss, d);
      float rms = rsqrtf(ss * (1.0f / 128.0f) + 1e-5f);
      x0 *= rms * wk0; x1 *= rms * wk1;
      float o0 = x0 * cv.x - x1 * sv.x;
      float o1 = x1 * cv.y + x0 * sv.y;
      u16x2 ou; ou.x = f2bf(o0); ou.y = f2bf(o1);
      *(u16x2*)&qkv[rowb + 3072] = ou;
    }
    {  // V -> registers for transposed store
      u16x2 vu = *(u16x2*)&qkv[rowb + 6144];
      if (r < 8) { va0[r] = vu.x; vb0[r] = vu.y; }
      else       { va1[r - 8] = vu.x; vb1[r - 8] = vu.y; }
    }
  }
  const size_t vbase = (size_t)h * 128 * 3584 + (size_t)(2 * lane) * 3584 + s0 + w * 16;
  *(u16x8*)&vt[vbase]            = va0;
  *(u16x8*)&vt[vbase + 8]        = va1;
  *(u16x8*)&vt[vbase + 3584]     = vb0;
  *(u16x8*)&vt[vbase + 3584 + 8] = vb1;
}

// ---------------- flash attention (32x32 MFMA, in-reg P, KVBLK=32, 3-buf) ---
__global__ __launch_bounds__(256, 2) void attn_kernel(
    const u16* __restrict__ qkv, const u16* __restrict__ vt,
    u16* __restrict__ aout) {
  const int bid = blockIdx.x;
  const int qt = bid / 24;
  const int rr = bid % 24;
  const int h = (rr % 8) * 3 + (rr / 8);
  const int tid = threadIdx.x, w = tid >> 6, lane = tid & 63;
  const int q32 = lane & 31, hi5 = lane >> 5;
  const int qbase = qt * 128 + w * 32;
  __shared__ u16 Klds[3][4096];
  __shared__ u16 Vlds[3][4096];

  bf16x8 aq[8];
  {
    const u16* qp = qkv + (size_t)(qbase + q32) * 9216 + h * 128 + hi5 * 8;
#pragma unroll
    for (int ds = 0; ds < 8; ++ds) aq[ds] = *(const bf16x8*)(qp + ds * 16);
  }
  float m_i = -1e30f, l_i = 0.f;
  f32x16 o[4];
#pragma unroll
  for (int dt = 0; dt < 4; ++dt)
#pragma unroll
    for (int r = 0; r < 16; ++r) o[dt][r] = 0.f;
  const size_t vhead = (size_t)h * 128 * 3584;

  auto STAGE_K = [&](int kt0, int b) {
    const char* src = (const char*)(qkv + (size_t)(kt0 + q32) * 9216 + 3072 + h * 128) + hi5 * 16;
    char* dst = (char*)Klds[b] + w * 2048 + lane * 16;
#pragma unroll
    for (int j = 0; j < 2; ++j)
      GLL16(src + (w * 2 + j) * 32, dst + j * 1024);
  };
  auto STAGE_V = [&](int kt0, int b) {
    char* dst = (char*)Vlds[b] + w * 2048 + lane * 16;
#pragma unroll
    for (int j = 0; j < 2; ++j) {
      const int u = w * 2 + j, dt = u >> 1, ks = u & 1;
      GLL16((const char*)(vt + vhead + (size_t)(dt * 32 + q32) * 3584 + kt0) + ks * 32 + hi5 * 16,
            dst + j * 1024);
    }
  };

  auto PACK = [&](const float* p, bf16x8* out2) {
    unsigned w0[4], w1[4];
#pragma unroll
    for (int g = 0; g < 4; ++g) {
      asm("v_cvt_pk_bf16_f32 %0, %1, %2" : "=v"(w0[g]) : "v"(p[4 * g + 0]), "v"(p[4 * g + 1]));
      asm("v_cvt_pk_bf16_f32 %0, %1, %2" : "=v"(w1[g]) : "v"(p[4 * g + 2]), "v"(p[4 * g + 3]));
    }
    asm("v_permlane32_swap_b32 %0, %1" : "+v"(w0[0]), "+v"(w0[1]));
    asm("v_permlane32_swap_b32 %0, %1" : "+v"(w1[0]), "+v"(w1[1]));
    asm("v_permlane32_swap_b32 %0, %1" : "+v"(w0[2]), "+v"(w0[3]));
    asm("v_permlane32_swap_b32 %0, %1" : "+v"(w1[2]), "+v"(w1[3]));
    u32x4 lo = {w0[0], w1[0], w0[1], w1[1]};
    u32x4 hi_ = {w0[2], w1[2], w0[3], w1[3]};
    out2[0] = __builtin_bit_cast(bf16x8, lo);
    out2[1] = __builtin_bit_cast(bf16x8, hi_);
  };

  const int NT = 112;
  STAGE_K(0, 0);   STAGE_V(0, 0);
  STAGE_K(32, 1);  STAGE_V(32, 1);
  int cur = 0;
  for (int t = 0; t < NT; ++t) {
    if (t + 1 < NT) VMC8(); else VMC0();
    BAR();

    f32x16 sA, sB;
#pragma unroll
    for (int r = 0; r < 16; ++r) { sA[r] = 0.f; sB[r] = 0.f; }
    __builtin_amdgcn_s_setprio(1);
#pragma unroll
    for (int ds = 0; ds < 4; ++ds) {
      bf16x8 k0 = *(const bf16x8*)((const char*)Klds[cur] + ds * 1024 + lane * 16);
      bf16x8 k1 = *(const bf16x8*)((const char*)Klds[cur] + (ds + 4) * 1024 + lane * 16);
      sA = __builtin_amdgcn_mfma_f32_32x32x16_bf16(k0, aq[ds], sA, 0, 0, 0);
      sB = __builtin_amdgcn_mfma_f32_32x32x16_bf16(k1, aq[ds + 4], sB, 0, 0, 0);
    }
    __builtin_amdgcn_s_setprio(0);

    float v[16];
#pragma unroll
    for (int r = 0; r < 16; ++r) v[r] = sA[r] + sB[r];
    float m8[8], m4[4], m2[2];
#pragma unroll
    for (int i = 0; i < 8; ++i) m8[i] = fmaxf(v[2 * i], v[2 * i + 1]);
#pragma unroll
    for (int i = 0; i < 4; ++i) m4[i] = fmaxf(m8[2 * i], m8[2 * i + 1]);
    m2[0] = fmaxf(m4[0], m4[1]); m2[1] = fmaxf(m4[2], m4[3]);
    float mx = fmaxf(m2[0], m2[1]);
    mx = fmaxf(mx, __shfl_xor(mx, 32));
    if (!__all(mx - m_i <= 8.f)) {
      float mnew = fmaxf(m_i, mx);
      float alpha = __builtin_amdgcn_exp2f(m_i - mnew);
      m_i = mnew;
      l_i *= alpha;
#pragma unroll
      for (int r = 0; r < 16; ++r) {
        int qr = (r & 3) + 8 * (r >> 2) + 4 * hi5;
        float ar = __shfl(alpha, qr);
#pragma unroll
        for (int dt = 0; dt < 4; ++dt) o[dt][r] *= ar;
      }
    }
    float p0[16];
#pragma unroll
    for (int r = 0; r < 16; ++r) p0[r] = __builtin_amdgcn_exp2f(v[r] - m_i);
    float s8[8], s4[4], s2[2];
#pragma unroll
    for (int i = 0; i < 8; ++i) s8[i] = p0[2 * i] + p0[2 * i + 1];
#pragma unroll
    for (int i = 0; i < 4; ++i) s4[i] = s8[2 * i] + s8[2 * i + 1];
    s2[0] = s4[0] + s4[1]; s2[1] = s4[2] + s4[3];
    float psum = s2[0] + s2[1];
    psum += __shfl_xor(psum, 32);
    l_i += psum;

    bf16x8 pa[2];
    PACK(p0, pa);

    __builtin_amdgcn_s_setprio(1);
#pragma unroll
    for (int dt = 0; dt < 4; ++dt) {
#pragma unroll
      for (int ks = 0; ks < 2; ++ks) {
        bf16x8 bv = *(const bf16x8*)((const char*)Vlds[cur] + (dt * 2 + ks) * 1024 + lane * 16);
        o[dt] = __builtin_amdgcn_mfma_f32_32x32x16_bf16(pa[ks], bv, o[dt], 0, 0, 0);
      }
    }
    __builtin_amdgcn_s_setprio(0);

    if (t + 2 < NT) {
      const int stg = cur ? cur - 1 : 2;
      STAGE_K((t + 2) * 32, stg);
      STAGE_V((t + 2) * 32, stg);
    }
    cur = (cur == 2) ? 0 : cur + 1;
  }

#pragma unroll
  for (int r = 0; r < 16; ++r) {
    const int qr = (r & 3) + 8 * (r >> 2) + 4 * hi5;
    const float lr = __shfl(l_i, qr);
    const float inv = 1.0f / lr;
    const size_t srow = (size_t)(qbase + qr) * 3072 + h * 128 + q32;
#pragma unroll
    for (int dt = 0; dt < 4; ++dt)
      aout[srow + dt * 32] = f2bf(o[dt][r] * inv);
  }
}

extern "C" void kernel_launch(void* const* d_in, const int* in_sizes, int n_in,
                              void* d_out, int out_size, void* d_ws, size_t ws_size,
                              hipStream_t stream) {
  (void)in_sizes; (void)n_in; (void)out_size; (void)ws_size;
  const float* hs    = (const float*)d_in[0];
  const float* ehs   = (const float*)d_in[1];
  const float* cosT  = (const float*)d_in[2];
  const float* sinT  = (const float*)d_in[3];
  const float* Wqkv  = (const float*)d_in[4];
  const float* Wadd  = (const float*)d_in[5];
  const float* bAdd  = (const float*)d_in[6];
  const float* nqw   = (const float*)d_in[7];
  const float* nkw   = (const float*)d_in[8];
  const float* naqw  = (const float*)d_in[9];
  const float* nakw  = (const float*)d_in[10];
  const float* Wout  = (const float*)d_in[11];
  const float* bout  = (const float*)d_in[12];
  const float* Waddo = (const float*)d_in[13];
  const float* baddo = (const float*)d_in[14];

  char* ws = (char*)d_ws;
  u16* Ain = (u16*)(ws);                       // [3584][3072]
  u16* WqI = (u16*)(ws + 22020096);            // [9216][3072]
  u16* WqE = WqI + (size_t)9216 * 3072;
  u16* WoI = (u16*)(ws + 135266304);           // [3072][3072]
  u16* WoE = WoI + (size_t)3072 * 3072;
  u16* qkv = (u16*)(ws + 173015040);           // [3584][9216]
  u16* vt   = Ain;  // alias: A_in dead after QKV GEMM
  u16* aout = WqI;  // alias: W_qkv dead after QKV GEMM

  cvt_all<<<4096, 256, 0, stream>>>(ehs, hs, Wqkv, Wadd, Wout, Waddo, (u16*)ws);

  gemm256<u16><<<dim3(504), 512, 0, stream>>>(Ain, WqI, WqE, nullptr, bAdd,
                                              qkv + (size_t)512 * 9216, qkv, 9216, 3072, 512);
  norm_rope<<<dim3(56, 24), 256, 0, stream>>>(qkv, vt, cosT, sinT, nqw, nkw, naqw, nakw);
  attn_kernel<<<dim3(672), 256, 0, stream>>>(qkv, vt, aout);
  float* outp = (float*)d_out;
  gemm192<<<dim3(224), 512, 0, stream>>>(aout, WoI, WoE, bout, baddo,
                                         outp, outp + (size_t)3072 * 3072, 3072, 3072, 512);
}

// Round 20
// 621.953 us; speedup vs baseline: 1.0345x; 1.0345x over previous
//
#include <hip/hip_runtime.h>

// Flux2 double-stream attention block, bf16 MFMA pipeline, f32 final output.
// Stages: fused cvt(f32->bf16) -> QKV GEMM (8-phase, counted vmcnt) ->
//         RMSnorm+RoPE(+V^T) -> flash attn (3-buf) -> out GEMM.
// R20 = exact revert to R18 (best measured: 623.3 us). Plateau evidence:
//   * QKV GEMM: 6 schedule variants (R10-R18) all ~233 us / 37.7% MfmaUtil
//     -> LDS-read/stall bound at this wave-tile geometry.
//   * attn: occupancy (R16) and ILP-chain (R17) variants neutral (~190 us).
//   * out-GEMM BN=192 variant (R19) regressed +20 us -> reverted to 256.
// ws layout (bytes):
//   [0,           22020096)  A_in bf16 [3584][3072]   } later aliased by V^T [24][128][3584]
//   [22020096,   135266304)  Wq bf16: img [9216][3072] then enc } later aliased by attn_out
//   [135266304,  173015040)  Wo bf16: img [3072][3072] then enc
//   [173015040,  239075328)  qkv bf16 [3584][9216]
// peak ws = 239,075,328 B.

typedef unsigned short u16;
typedef __attribute__((ext_vector_type(2))) unsigned short u16x2;
typedef __attribute__((ext_vector_type(4))) unsigned short u16x4;
typedef __attribute__((ext_vector_type(8))) unsigned short u16x8;
typedef __attribute__((ext_vector_type(8))) short bf16x8;
typedef __attribute__((ext_vector_type(4))) float f32x4;
typedef __attribute__((ext_vector_type(16))) float f32x16;
typedef __attribute__((ext_vector_type(4))) unsigned u32x4;

#define DEV __device__ __forceinline__

DEV u16 f2bf(float f) {
  unsigned u = __builtin_bit_cast(unsigned, f);
  u = (u + 0x7FFFu + ((u >> 16) & 1u)) >> 16;   // RNE
  return (u16)u;
}
DEV float bf2f(u16 s) { return __builtin_bit_cast(float, (unsigned)s << 16); }

DEV void store_out(u16* p, float v)  { *p = f2bf(v); }
DEV void store_out(float* p, float v) { *p = v; }

#define AS1(p) (const __attribute__((address_space(1))) void*)(p)
#define AS3(p) (__attribute__((address_space(3))) void*)(p)
#define GLL16(g, l) __builtin_amdgcn_global_load_lds(AS1(g), AS3(l), 16, 0, 0)

#define BAR() do { asm volatile("" ::: "memory"); __builtin_amdgcn_s_barrier(); \
                   asm volatile("" ::: "memory"); } while (0)
#define LGKM0() asm volatile("s_waitcnt lgkmcnt(0)" ::: "memory")
#define VMC8() asm volatile("s_waitcnt vmcnt(8)" ::: "memory")
#define VMC6() asm volatile("s_waitcnt vmcnt(6)" ::: "memory")
#define VMC0() asm volatile("s_waitcnt vmcnt(0)" ::: "memory")

// ---------------- fused fp32 -> bf16 convert (6 segments, 1 dispatch) -------
__global__ __launch_bounds__(256) void cvt_all(
    const float* __restrict__ s0, const float* __restrict__ s1,
    const float* __restrict__ s2, const float* __restrict__ s3,
    const float* __restrict__ s4, const float* __restrict__ s5,
    u16* __restrict__ ws16) {
  constexpr int B1 = 393216, B2 = 2752512, B3 = 9830400,
                B4 = 16908288, B5 = 19267584, B6 = 21626880;
  int i = blockIdx.x * blockDim.x + threadIdx.x;
  int stride = gridDim.x * blockDim.x;
  for (; i < B6; i += stride) {
    const float* src; size_t off; u16* dst;
    if (i < B1)      { src = s0; off = i;      dst = ws16; }
    else if (i < B2) { src = s1; off = i - B1; dst = ws16 + 1572864; }
    else if (i < B3) { src = s2; off = i - B2; dst = ws16 + 11010048; }
    else if (i < B4) { src = s3; off = i - B3; dst = ws16 + 39321600; }
    else if (i < B5) { src = s4; off = i - B4; dst = ws16 + 67633152; }
    else             { src = s5; off = i - B5; dst = ws16 + 77070336; }
    float4 v = reinterpret_cast<const float4*>(src)[off];
    u16x4 o;
    o.x = f2bf(v.x); o.y = f2bf(v.y); o.z = f2bf(v.z); o.w = f2bf(v.w);
    reinterpret_cast<u16x4*>(dst)[off] = o;
  }
}

// ---------------- GEMM: 8-phase 256x256, BK=64, counted vmcnt (ph3/ph7) -----
template <typename OT>
__global__ __launch_bounds__(512, 2) void gemm256(
    const u16* __restrict__ A,
    const u16* __restrict__ Bimg, const u16* __restrict__ Benc,
    const float* __restrict__ biasImg, const float* __restrict__ biasEnc,
    OT* __restrict__ Cimg, OT* __restrict__ Cenc,
    int N, int K, int split) {
  const int bid = blockIdx.x;
  const int ntn = N >> 8;
  const int CN = ntn >> 2;
  const int x = bid & 7, i5 = bid >> 3;
  const int mt = (x >> 2) * 7 + i5 / CN;
  const int nt = (x & 3) * CN + i5 % CN;
  const int m0 = mt << 8, n0 = nt << 8;
  const u16* B = (m0 < split) ? Benc : Bimg;
  const float* bias = (m0 < split) ? biasEnc : biasImg;

  __shared__ u16 lds[2][2][2][8192];  // [dbuf][A=0/B=1][half][16KB] = 128 KiB

  const int tid = threadIdx.x, w = tid >> 6, lane = tid & 63;
  const int wm = w >> 2, wn = w & 3;
  const int q = lane & 15, hi = lane >> 4;
  const size_t ldb = (size_t)K * 2;

  f32x4 acc[8][4];
#pragma unroll
  for (int i = 0; i < 8; ++i)
#pragma unroll
    for (int j = 0; j < 4; ++j)
#pragma unroll
      for (int r = 0; r < 4; ++r) acc[i][j][r] = 0.f;

  auto STG_B = [&](int kt, int h) {
    const int d = kt & 1;
    char* dst = (char*)&lds[d][1][h][0] + w * 1024 + lane * 16;
#pragma unroll
    for (int g = 0; g < 2; ++g) {
      const int n = g * 8 + w;
      const char* src = (const char*)B + (size_t)(n0 + h * 128 + (n >> 1) * 16 + q) * ldb
                        + (size_t)kt * 128 + (n & 1) * 64 + hi * 16;
      GLL16(src, dst + g * 8192);
    }
  };
  auto STG_A = [&](int kt, int g) {
    const int d = kt & 1;
#pragma unroll
    for (int h = 0; h < 2; ++h) {
      const int n = g * 8 + w;
      const char* src = (const char*)A + (size_t)(m0 + h * 128 + (n >> 1) * 16 + q) * ldb
                        + (size_t)kt * 128 + (n & 1) * 64 + hi * 16;
      GLL16(src, (char*)&lds[d][0][h][0] + n * 1024 + lane * 16);
    }
  };
  auto LDA = [&](int d, int i, int ks) -> bf16x8 {
    return *(const bf16x8*)((const char*)&lds[d][0][wm][0] + (i * 2 + ks) * 1024 + lane * 16);
  };
  auto LDB = [&](int d, int j, int ks) -> bf16x8 {
    return *(const bf16x8*)((const char*)&lds[d][1][wn >> 1][0]
                            + (((wn & 1) * 4 + j) * 2 + ks) * 1024 + lane * 16);
  };

  bf16x8 bfr[4][2];
  // wmode: 0 = no vmcnt, 1 = vmcnt(6), 2 = vmcnt(0)
  auto PH = [&](int d, int ph, auto stageFn, int wmode) {
    if (ph == 0) {
#pragma unroll
      for (int j = 0; j < 4; ++j)
#pragma unroll
        for (int ks = 0; ks < 2; ++ks) bfr[j][ks] = LDB(d, j, ks);
    }
    bf16x8 af[2][2];
#pragma unroll
    for (int m = 0; m < 2; ++m)
#pragma unroll
      for (int ks = 0; ks < 2; ++ks) af[m][ks] = LDA(d, 2 * ph + m, ks);
    stageFn();
    BAR();
    LGKM0();
    __builtin_amdgcn_s_setprio(1);
#pragma unroll
    for (int m = 0; m < 2; ++m)
#pragma unroll
      for (int j = 0; j < 4; ++j)
#pragma unroll
        for (int ks = 0; ks < 2; ++ks)
          acc[2 * ph + m][j] = __builtin_amdgcn_mfma_f32_16x16x32_bf16(
              af[m][ks], bfr[j][ks], acc[2 * ph + m][j], 0, 0, 0);
    __builtin_amdgcn_s_setprio(0);
    if (wmode == 1)      VMC6();
    else if (wmode == 2) VMC0();
    BAR();
  };

  const int NT2 = K >> 7;
  STG_B(0, 0); STG_B(0, 1); STG_A(0, 0); STG_A(0, 1);
  STG_B(1, 0); STG_B(1, 1); STG_A(1, 0);
  VMC6();
  BAR();
  for (int t = 0; t < NT2; ++t) {
    const bool full = (t + 1 < NT2);
    const int w3 = full ? 1 : 2;
    PH(0, 0, [&] { STG_A(2 * t + 1, 1); }, 0);
    PH(0, 1, [&] { if (full) STG_B(2 * t + 2, 0); }, 0);
    PH(0, 2, [&] { if (full) STG_B(2 * t + 2, 1); }, 0);
    PH(0, 3, [&] { if (full) STG_A(2 * t + 2, 0); }, w3);
    PH(1, 0, [&] { if (full) STG_A(2 * t + 2, 1); }, 0);
    PH(1, 1, [&] { if (full) STG_B(2 * t + 3, 0); }, 0);
    PH(1, 2, [&] { if (full) STG_B(2 * t + 3, 1); }, 0);
    PH(1, 3, [&] { if (full) STG_A(2 * t + 3, 0); }, w3);
  }

#pragma unroll
  for (int i = 0; i < 8; ++i) {
    int rbase = m0 + wm * 128 + i * 16 + (hi << 2);
#pragma unroll
    for (int j = 0; j < 4; ++j) {
      int col = n0 + wn * 64 + j * 16 + q;
      float bv = bias ? bias[col] : 0.f;
#pragma unroll
      for (int r = 0; r < 4; ++r) {
        int row = rbase + r;
        float v = acc[i][j][r] + bv;
        if (row < split) store_out(&Cenc[(size_t)row * N + col], v);
        else             store_out(&Cimg[(size_t)(row - split) * N + col], v);
      }
    }
  }
}

// ---------------- per-head RMSnorm(q,k) + RoPE(q,k), emit V^T -----------------
// Q pre-scaled by log2(e)/sqrt(128) so attn scores land in log2 units.
__global__ __launch_bounds__(256) void norm_rope(
    u16* __restrict__ qkv, u16* __restrict__ vt,
    const float* __restrict__ cosT, const float* __restrict__ sinT,
    const float* __restrict__ nqw_img, const float* __restrict__ nkw_img,
    const float* __restrict__ nqw_enc, const float* __restrict__ nkw_enc) {
  const int h = blockIdx.y;
  const int s0 = blockIdx.x * 64;
  const int tid = threadIdx.x, w = tid >> 6, lane = tid & 63;
  const bool enc = (s0 < 512);
  const float* nqw = enc ? nqw_enc : nqw_img;
  const float* nkw = enc ? nkw_enc : nkw_img;
  const float SCL = 0.12751743f;  // log2(e)/sqrt(128)
  const float wq0 = nqw[2 * lane], wq1 = nqw[2 * lane + 1];
  const float wk0 = nkw[2 * lane], wk1 = nkw[2 * lane + 1];
  u16x8 va0, va1, vb0, vb1;
#pragma unroll
  for (int r = 0; r < 16; ++r) {
    const int s = s0 + w * 16 + r;
    const size_t rowb = (size_t)s * 9216 + h * 128 + 2 * lane;
    float2 cv = *(const float2*)&cosT[(size_t)s * 128 + 2 * lane];
    float2 sv = *(const float2*)&sinT[(size_t)s * 128 + 2 * lane];
    {  // Q
      u16x2 qu = *(u16x2*)&qkv[rowb];
      float x0 = bf2f(qu.x), x1 = bf2f(qu.y);
      float ss = x0 * x0 + x1 * x1;
#pragma unroll
      for (int d = 1; d < 64; d <<= 1) ss += __shfl_xor(ss, d);
      float rms = rsqrtf(ss * (1.0f / 128.0f) + 1e-5f);
      x0 *= rms * wq0; x1 *= rms * wq1;
      float o0 = (x0 * cv.x - x1 * sv.x) * SCL;
      float o1 = (x1 * cv.y + x0 * sv.y) * SCL;
      u16x2 ou; ou.x = f2bf(o0); ou.y = f2bf(o1);
      *(u16x2*)&qkv[rowb] = ou;
    }
    {  // K
      u16x2 ku = *(u16x2*)&qkv[rowb + 3072];
      float x0 = bf2f(ku.x), x1 = bf2f(ku.y);
      float ss = x0 * x0 + x1 * x1;
#pragma unroll
      for (int d = 1; d < 64; d <<= 1) ss += __shfl_xor(ss, d);
      float rms = rsqrtf(ss * (1.0f / 128.0f) + 1e-5f);
      x0 *= rms * wk0; x1 *= rms * wk1;
      float o0 = x0 * cv.x - x1 * sv.x;
      float o1 = x1 * cv.y + x0 * sv.y;
      u16x2 ou; ou.x = f2bf(o0); ou.y = f2bf(o1);
      *(u16x2*)&qkv[rowb + 3072] = ou;
    }
    {  // V -> registers for transposed store
      u16x2 vu = *(u16x2*)&qkv[rowb + 6144];
      if (r < 8) { va0[r] = vu.x; vb0[r] = vu.y; }
      else       { va1[r - 8] = vu.x; vb1[r - 8] = vu.y; }
    }
  }
  const size_t vbase = (size_t)h * 128 * 3584 + (size_t)(2 * lane) * 3584 + s0 + w * 16;
  *(u16x8*)&vt[vbase]            = va0;
  *(u16x8*)&vt[vbase + 8]        = va1;
  *(u16x8*)&vt[vbase + 3584]     = vb0;
  *(u16x8*)&vt[vbase + 3584 + 8] = vb1;
}

// ---------------- flash attention (32x32 MFMA, in-reg P, KVBLK=32, 3-buf) ---
__global__ __launch_bounds__(256, 2) void attn_kernel(
    const u16* __restrict__ qkv, const u16* __restrict__ vt,
    u16* __restrict__ aout) {
  const int bid = blockIdx.x;
  const int qt = bid / 24;
  const int rr = bid % 24;
  const int h = (rr % 8) * 3 + (rr / 8);
  const int tid = threadIdx.x, w = tid >> 6, lane = tid & 63;
  const int q32 = lane & 31, hi5 = lane >> 5;
  const int qbase = qt * 128 + w * 32;
  __shared__ u16 Klds[3][4096];
  __shared__ u16 Vlds[3][4096];

  bf16x8 aq[8];
  {
    const u16* qp = qkv + (size_t)(qbase + q32) * 9216 + h * 128 + hi5 * 8;
#pragma unroll
    for (int ds = 0; ds < 8; ++ds) aq[ds] = *(const bf16x8*)(qp + ds * 16);
  }
  float m_i = -1e30f, l_i = 0.f;
  f32x16 o[4];
#pragma unroll
  for (int dt = 0; dt < 4; ++dt)
#pragma unroll
    for (int r = 0; r < 16; ++r) o[dt][r] = 0.f;
  const size_t vhead = (size_t)h * 128 * 3584;

  auto STAGE_K = [&](int kt0, int b) {
    const char* src = (const char*)(qkv + (size_t)(kt0 + q32) * 9216 + 3072 + h * 128) + hi5 * 16;
    char* dst = (char*)Klds[b] + w * 2048 + lane * 16;
#pragma unroll
    for (int j = 0; j < 2; ++j)
      GLL16(src + (w * 2 + j) * 32, dst + j * 1024);
  };
  auto STAGE_V = [&](int kt0, int b) {
    char* dst = (char*)Vlds[b] + w * 2048 + lane * 16;
#pragma unroll
    for (int j = 0; j < 2; ++j) {
      const int u = w * 2 + j, dt = u >> 1, ks = u & 1;
      GLL16((const char*)(vt + vhead + (size_t)(dt * 32 + q32) * 3584 + kt0) + ks * 32 + hi5 * 16,
            dst + j * 1024);
    }
  };

  auto PACK = [&](const float* p, bf16x8* out2) {
    unsigned w0[4], w1[4];
#pragma unroll
    for (int g = 0; g < 4; ++g) {
      asm("v_cvt_pk_bf16_f32 %0, %1, %2" : "=v"(w0[g]) : "v"(p[4 * g + 0]), "v"(p[4 * g + 1]));
      asm("v_cvt_pk_bf16_f32 %0, %1, %2" : "=v"(w1[g]) : "v"(p[4 * g + 2]), "v"(p[4 * g + 3]));
    }
    asm("v_permlane32_swap_b32 %0, %1" : "+v"(w0[0]), "+v"(w0[1]));
    asm("v_permlane32_swap_b32 %0, %1" : "+v"(w1[0]), "+v"(w1[1]));
    asm("v_permlane32_swap_b32 %0, %1" : "+v"(w0[2]), "+v"(w0[3]));
    asm("v_permlane32_swap_b32 %0, %1" : "+v"(w1[2]), "+v"(w1[3]));
    u32x4 lo = {w0[0], w1[0], w0[1], w1[1]};
    u32x4 hi_ = {w0[2], w1[2], w0[3], w1[3]};
    out2[0] = __builtin_bit_cast(bf16x8, lo);
    out2[1] = __builtin_bit_cast(bf16x8, hi_);
  };

  const int NT = 112;
  STAGE_K(0, 0);   STAGE_V(0, 0);
  STAGE_K(32, 1);  STAGE_V(32, 1);
  int cur = 0;
  for (int t = 0; t < NT; ++t) {
    if (t + 1 < NT) VMC8(); else VMC0();
    BAR();

    f32x16 sA, sB;
#pragma unroll
    for (int r = 0; r < 16; ++r) { sA[r] = 0.f; sB[r] = 0.f; }
    __builtin_amdgcn_s_setprio(1);
#pragma unroll
    for (int ds = 0; ds < 4; ++ds) {
      bf16x8 k0 = *(const bf16x8*)((const char*)Klds[cur] + ds * 1024 + lane * 16);
      bf16x8 k1 = *(const bf16x8*)((const char*)Klds[cur] + (ds + 4) * 1024 + lane * 16);
      sA = __builtin_amdgcn_mfma_f32_32x32x16_bf16(k0, aq[ds], sA, 0, 0, 0);
      sB = __builtin_amdgcn_mfma_f32_32x32x16_bf16(k1, aq[ds + 4], sB, 0, 0, 0);
    }
    __builtin_amdgcn_s_setprio(0);

    float v[16];
#pragma unroll
    for (int r = 0; r < 16; ++r) v[r] = sA[r] + sB[r];
    float m8[8], m4[4], m2[2];
#pragma unroll
    for (int i = 0; i < 8; ++i) m8[i] = fmaxf(v[2 * i], v[2 * i + 1]);
#pragma unroll
    for (int i = 0; i < 4; ++i) m4[i] = fmaxf(m8[2 * i], m8[2 * i + 1]);
    m2[0] = fmaxf(m4[0], m4[1]); m2[1] = fmaxf(m4[2], m4[3]);
    float mx = fmaxf(m2[0], m2[1]);
    mx = fmaxf(mx, __shfl_xor(mx, 32));
    if (!__all(mx - m_i <= 8.f)) {
      float mnew = fmaxf(m_i, mx);
      float alpha = __builtin_amdgcn_exp2f(m_i - mnew);
      m_i = mnew;
      l_i *= alpha;
#pragma unroll
      for (int r = 0; r < 16; ++r) {
        int qr = (r & 3) + 8 * (r >> 2) + 4 * hi5;
        float ar = __shfl(alpha, qr);
#pragma unroll
        for (int dt = 0; dt < 4; ++dt) o[dt][r] *= ar;
      }
    }
    float p0[16];
#pragma unroll
    for (int r = 0; r < 16; ++r) p0[r] = __builtin_amdgcn_exp2f(v[r] - m_i);
    float s8[8], s4[4], s2[2];
#pragma unroll
    for (int i = 0; i < 8; ++i) s8[i] = p0[2 * i] + p0[2 * i + 1];
#pragma unroll
    for (int i = 0; i < 4; ++i) s4[i] = s8[2 * i] + s8[2 * i + 1];
    s2[0] = s4[0] + s4[1]; s2[1] = s4[2] + s4[3];
    float psum = s2[0] + s2[1];
    psum += __shfl_xor(psum, 32);
    l_i += psum;

    bf16x8 pa[2];
    PACK(p0, pa);

    __builtin_amdgcn_s_setprio(1);
#pragma unroll
    for (int dt = 0; dt < 4; ++dt) {
#pragma unroll
      for (int ks = 0; ks < 2; ++ks) {
        bf16x8 bv = *(const bf16x8*)((const char*)Vlds[cur] + (dt * 2 + ks) * 1024 + lane * 16);
        o[dt] = __builtin_amdgcn_mfma_f32_32x32x16_bf16(pa[ks], bv, o[dt], 0, 0, 0);
      }
    }
    __builtin_amdgcn_s_setprio(0);

    if (t + 2 < NT) {
      const int stg = cur ? cur - 1 : 2;
      STAGE_K((t + 2) * 32, stg);
      STAGE_V((t + 2) * 32, stg);
    }
    cur = (cur == 2) ? 0 : cur + 1;
  }

#pragma unroll
  for (int r = 0; r < 16; ++r) {
    const int qr = (r & 3) + 8 * (r >> 2) + 4 * hi5;
    const float lr = __shfl(l_i, qr);
    const float inv = 1.0f / lr;
    const size_t srow = (size_t)(qbase + qr) * 3072 + h * 128 + q32;
#pragma unroll
    for (int dt = 0; dt < 4; ++dt)
      aout[srow + dt * 32] = f2bf(o[dt][r] * inv);
  }
}

extern "C" void kernel_launch(void* const* d_in, const int* in_sizes, int n_in,
                              void* d_out, int out_size, void* d_ws, size_t ws_size,
                              hipStream_t stream) {
  (void)in_sizes; (void)n_in; (void)out_size; (void)ws_size;
  const float* hs    = (const float*)d_in[0];
  const float* ehs   = (const float*)d_in[1];
  const float* cosT  = (const float*)d_in[2];
  const float* sinT  = (const float*)d_in[3];
  const float* Wqkv  = (const float*)d_in[4];
  const float* Wadd  = (const float*)d_in[5];
  const float* bAdd  = (const float*)d_in[6];
  const float* nqw   = (const float*)d_in[7];
  const float* nkw   = (const float*)d_in[8];
  const float* naqw  = (const float*)d_in[9];
  const float* nakw  = (const float*)d_in[10];
  const float* Wout  = (const float*)d_in[11];
  const float* bout  = (const float*)d_in[12];
  const float* Waddo = (const float*)d_in[13];
  const float* baddo = (const float*)d_in[14];

  char* ws = (char*)d_ws;
  u16* Ain = (u16*)(ws);                       // [3584][3072]
  u16* WqI = (u16*)(ws + 22020096);            // [9216][3072]
  u16* WqE = WqI + (size_t)9216 * 3072;
  u16* WoI = (u16*)(ws + 135266304);           // [3072][3072]
  u16* WoE = WoI + (size_t)3072 * 3072;
  u16* qkv = (u16*)(ws + 173015040);           // [3584][9216]
  u16* vt   = Ain;  // alias: A_in dead after QKV GEMM
  u16* aout = WqI;  // alias: W_qkv dead after QKV GEMM

  cvt_all<<<4096, 256, 0, stream>>>(ehs, hs, Wqkv, Wadd, Wout, Waddo, (u16*)ws);

  gemm256<u16><<<dim3(504), 512, 0, stream>>>(Ain, WqI, WqE, nullptr, bAdd,
                                              qkv + (size_t)512 * 9216, qkv, 9216, 3072, 512);
  norm_rope<<<dim3(56, 24), 256, 0, stream>>>(qkv, vt, cosT, sinT, nqw, nkw, naqw, nakw);
  attn_kernel<<<dim3(672), 256, 0, stream>>>(qkv, vt, aout);
  float* outp = (float*)d_out;
  gemm256<float><<<dim3(168), 512, 0, stream>>>(aout, WoI, WoE, bout, baddo,
                                                outp, outp + (size_t)3072 * 3072, 3072, 3072, 512);
}